// Round 3
// baseline (784.535 us; speedup 1.0000x reference)
//
#include <hip/hip_runtime.h>
#include <hip/hip_bf16.h>

// B=4, S=2048, H=1024, heads=16, d=64
// d_out: out f32[8192][1024], avg f32[4][2048][2048]
// ws: Qb bf16[8192][1024] (PRESCALED by 0.125*log2e), Kb bf16[8192][1024],
//     Vt bf16[4][64][2048], AOb bf16[8192][64]
// cast scratch (qbf,kbf,wqb,wkb) lives in the avg region of d_out until attn runs.

typedef float f32x4 __attribute__((ext_vector_type(4)));
typedef short s16x8 __attribute__((ext_vector_type(8)));

#define DEVI static __device__ __forceinline__
#define MFMA16(a, b, c) __builtin_amdgcn_mfma_f32_16x16x32_bf16(a, b, c, 0, 0, 0)
#define WAITV(N) asm volatile("s_waitcnt vmcnt(" #N ")" ::: "memory")
#define WAITL()  asm volatile("s_waitcnt lgkmcnt(0)" ::: "memory")
#define BAR()    __builtin_amdgcn_s_barrier()

DEVI unsigned short f2bf(float f) {
  union { float f; unsigned u; } v; v.f = f;
  return (unsigned short)((v.u + 0x7fffu + ((v.u >> 16) & 1u)) >> 16);
}

DEVI s16x8 pack2(f32x4 lo, f32x4 hi) {
  s16x8 r;
  r[0] = (short)f2bf(lo[0]); r[1] = (short)f2bf(lo[1]);
  r[2] = (short)f2bf(lo[2]); r[3] = (short)f2bf(lo[3]);
  r[4] = (short)f2bf(hi[0]); r[5] = (short)f2bf(hi[1]);
  r[6] = (short)f2bf(hi[2]); r[7] = (short)f2bf(hi[3]);
  return r;
}

DEVI float fast_exp2(float x) {
#if __has_builtin(__builtin_amdgcn_exp2f)
  return __builtin_amdgcn_exp2f(x);
#else
  return exp2f(x);
#endif
}

DEVI void gld16(const void* g, const void* lds) {
  __builtin_amdgcn_global_load_lds(
      (const __attribute__((address_space(1))) unsigned int*)g,
      (__attribute__((address_space(3))) unsigned int*)lds, 16, 0, 0);
}

// ---------------- Kernel 0: cast f32 -> bf16 (q, k, Wq, Wk) ---------------
__global__ __launch_bounds__(256) void cast_bf16(
    const float* __restrict__ q, const float* __restrict__ k,
    const float* __restrict__ Wq, const float* __restrict__ Wk,
    unsigned short* __restrict__ qbf, unsigned short* __restrict__ kbf,
    unsigned short* __restrict__ wqb, unsigned short* __restrict__ wkb) {
  const int bid = blockIdx.x;
  const float* src; unsigned short* dst; size_t base;
  if (bid < 1024)      { src = q;  dst = qbf; base = (size_t)bid * 8192; }
  else if (bid < 2048) { src = k;  dst = kbf; base = (size_t)(bid - 1024) * 8192; }
  else if (bid < 2176) { src = Wq; dst = wqb; base = (size_t)(bid - 2048) * 8192; }
  else                 { src = Wk; dst = wkb; base = (size_t)(bid - 2176) * 8192; }
#pragma unroll
  for (int j = 0; j < 4; ++j) {
    const size_t i = base + (size_t)j * 2048 + threadIdx.x * 8;
    const f32x4 lo = *(const f32x4*)&src[i];
    const f32x4 hi = *(const f32x4*)&src[i + 4];
    *(s16x8*)&dst[i] = pack2(lo, hi);
  }
}

// ---------------- Kernel 1: Q/K projection, bf16 MFMA, async staged -------
// C[m,n] = (sum_k A[m,k]*W[n,k] + bias[n]) * oscale, bf16 out.
// 128x128 tile, BK=64, global_load_lds double-buffer, XOR-swizzled LDS.
__global__ __launch_bounds__(256, 2) void proj_qk(
    const unsigned short* __restrict__ qbf, const unsigned short* __restrict__ kbf,
    const unsigned short* __restrict__ wqb, const unsigned short* __restrict__ wkb,
    const float* __restrict__ bq, const float* __restrict__ bk,
    unsigned short* __restrict__ Qb, unsigned short* __restrict__ Kb) {
  __shared__ unsigned short As[2][128 * 64];
  __shared__ unsigned short Bs[2][128 * 64];
  const unsigned short* A = blockIdx.z ? kbf : qbf;
  const unsigned short* Bw = blockIdx.z ? wkb : wqb;
  const float* bias = blockIdx.z ? bk : bq;
  unsigned short* C = blockIdx.z ? Kb : Qb;
  const float oscale = blockIdx.z ? 1.0f : 0.18033688011112042f;  // 0.125*log2(e)

  const int t = threadIdx.x, lane = t & 63, w = t >> 6;
  const int wm = w >> 1, wn = w & 1;
  const int fr = lane & 15, g = lane >> 4;
  const int m0 = blockIdx.x * 128, n0 = blockIdx.y * 128;

  const int srow = w * 32 + (lane >> 3);          // + j*8
  const int gby = ((lane & 7) << 4);              // ^ ((row&7)<<4)

  f32x4 acc[4][4];
#pragma unroll
  for (int i = 0; i < 4; ++i)
#pragma unroll
    for (int j = 0; j < 4; ++j) acc[i][j] = (f32x4){0.f, 0.f, 0.f, 0.f};

#define PSTAGE(ks)                                                          \
  {                                                                         \
    const int _buf = (ks) & 1;                                              \
    _Pragma("unroll") for (int j = 0; j < 4; ++j) {                         \
      const int row = srow + j * 8;                                         \
      const int gb = gby ^ ((row & 7) << 4);                                \
      gld16(A + (size_t)(m0 + row) * 1024 + (ks) * 64 + (gb >> 1),          \
            &As[_buf][w * 2048 + j * 512]);                                 \
      gld16(Bw + (size_t)(n0 + row) * 1024 + (ks) * 64 + (gb >> 1),         \
            &Bs[_buf][w * 2048 + j * 512]);                                 \
    }                                                                       \
  }

  PSTAGE(0);
  for (int ks = 0; ks < 16; ++ks) {
    WAITL(); BAR();
    if (ks < 15) { PSTAGE(ks + 1); WAITV(8); } else { WAITV(0); }
    __builtin_amdgcn_sched_barrier(0);
    const unsigned short* Ab = As[ks & 1];
    const unsigned short* Bb = Bs[ks & 1];
    s16x8 af[2][4], bf[2][4];
#pragma unroll
    for (int k = 0; k < 2; ++k) {
#pragma unroll
      for (int mt = 0; mt < 4; ++mt) {
        const int row = wm * 64 + mt * 16 + fr;
        af[k][mt] = *(const s16x8*)&Ab[row * 64 + (((k * 64 + g * 16) ^ ((row & 7) << 4)) >> 1)];
      }
#pragma unroll
      for (int nt = 0; nt < 4; ++nt) {
        const int row = wn * 64 + nt * 16 + fr;
        bf[k][nt] = *(const s16x8*)&Bb[row * 64 + (((k * 64 + g * 16) ^ ((row & 7) << 4)) >> 1)];
      }
    }
#pragma unroll
    for (int k = 0; k < 2; ++k)
#pragma unroll
      for (int mt = 0; mt < 4; ++mt)
#pragma unroll
        for (int nt = 0; nt < 4; ++nt)
          acc[mt][nt] = MFMA16(af[k][mt], bf[k][nt], acc[mt][nt]);
  }

#pragma unroll
  for (int nt = 0; nt < 4; ++nt) {
    const int col = n0 + wn * 64 + nt * 16 + fr;
    const float bb = bias[col];
#pragma unroll
    for (int mt = 0; mt < 4; ++mt) {
      const int row = m0 + wm * 64 + mt * 16 + g * 4;
#pragma unroll
      for (int r = 0; r < 4; ++r)
        C[(size_t)(row + r) * 1024 + col] = f2bf((acc[mt][nt][r] + bb) * oscale);
    }
  }
#undef PSTAGE
}

// ---------------- Kernel 2: V projection, stored TRANSPOSED Vt[b][d][s] ----
__global__ __launch_bounds__(256, 2) void proj_v(
    const float* __restrict__ val, const float* __restrict__ Wv,
    const float* __restrict__ bv, unsigned short* __restrict__ Vt) {
  __shared__ short As2[64][32];
  __shared__ short Bs2[64][32];
  const int t = threadIdx.x, lane = t & 63, w = t >> 6;
  const int fr = lane & 15, g = lane >> 4;
  const int m0 = blockIdx.x * 64;
  const int sr = t >> 2, sc = (t & 3) * 8;
  const float* Ap = val + (size_t)(m0 + sr) * 1024 + sc;
  const float* Bp = Wv + (size_t)sr * 1024 + sc;

  f32x4 acc[4];
#pragma unroll
  for (int i = 0; i < 4; ++i) acc[i] = (f32x4){0.f, 0.f, 0.f, 0.f};

  for (int kt = 0; kt < 32; ++kt) {
    const f32x4 a0 = *(const f32x4*)Ap, a1 = *(const f32x4*)(Ap + 4);
    const f32x4 b0 = *(const f32x4*)Bp, b1 = *(const f32x4*)(Bp + 4);
    Ap += 32; Bp += 32;
    __syncthreads();
    *(s16x8*)&As2[sr][sc] = pack2(a0, a1);
    *(s16x8*)&Bs2[sr][sc] = pack2(b0, b1);
    __syncthreads();
    const s16x8 a = *(const s16x8*)&As2[w * 16 + fr][g * 8];
#pragma unroll
    for (int nt = 0; nt < 4; ++nt) {
      const s16x8 b = *(const s16x8*)&Bs2[nt * 16 + fr][g * 8];
      acc[nt] = MFMA16(a, b, acc[nt]);
    }
  }
#pragma unroll
  for (int nt = 0; nt < 4; ++nt) {
    const int d = nt * 16 + fr;
    const float bb = bv[d];
#pragma unroll
    for (int r = 0; r < 4; ++r) {
      const int srw = m0 + w * 16 + g * 4 + r;
      Vt[((size_t)(srw >> 11) * 64 + d) * 2048 + (srw & 2047)] = f2bf(acc[nt][r] + bb);
    }
  }
}

// ---------------- Kernel 3: fused scores -> softmax -> head-avg -----------
// Block = (batch, 32 q-rows), 16 waves = (q-half) x (key-eighth).
// Two passes (sum, then normalize+accumulate), no max-subtraction (scores
// bounded ~|4|), K staged via global_load_lds double-buffer + XOR swizzle.
__global__ __launch_bounds__(1024, 4) void attn_avg(
    const unsigned short* __restrict__ Qb, const unsigned short* __restrict__ Kb,
    float* __restrict__ avg_out) {
  __shared__ unsigned short Qs[32 * 1032];     // padded rows: 2-way banks
  __shared__ unsigned short Ks[2][256 * 64];   // 2 x 32KB double buffer
  __shared__ float sums[16][32][8];            // [head][qrow][key-eighth]

  const int t = threadIdx.x, lane = t & 63, w = t >> 6;
  const int fr = lane & 15, g = lane >> 4;
  const int qh = w >> 3, kw = w & 7;
  int bx = blockIdx.x;
  bx = (bx & 7) * 32 + (bx >> 3);  // XCD-contiguous (256 = 8*32)
  const int b = bx >> 6, q0 = (bx & 63) * 32;

  // stage Q tile (32 rows x 1024), padded to 1032
  {
    const unsigned short* Qg = Qb + (size_t)(b * 2048 + q0) * 1024;
#pragma unroll
    for (int j = 0; j < 4; ++j) {
      const int idx = j * 1024 + t;            // 8-elem group
      const int row = idx >> 7, col = (idx & 127) << 3;
      *(s16x8*)&Qs[row * 1032 + col] = *(const s16x8*)&Qg[(size_t)row * 1024 + col];
    }
  }

  const int srow = w * 16 + (lane >> 3);       // + j*8, rows 0..255
  const int gby = (lane & 7) << 4;

#define ASTAGE(s)                                                            \
  {                                                                          \
    const int _h = ((s) >> 3) & 15, _ktp = (s) & 7, _buf = (s) & 1;          \
    _Pragma("unroll") for (int j = 0; j < 2; ++j) {                          \
      const int row = srow + j * 8;                                          \
      const int key = (b << 11) + ((row >> 5) << 8) + (_ktp << 5) + (row & 31); \
      const int gb = gby ^ ((row & 7) << 4);                                 \
      gld16(Kb + (size_t)key * 1024 + _h * 64 + (gb >> 1),                   \
            &Ks[_buf][w * 1024 + j * 512]);                                  \
    }                                                                        \
  }

  float avg[16][4];
#pragma unroll
  for (int kt = 0; kt < 16; ++kt)
#pragma unroll
    for (int r = 0; r < 4; ++r) avg[kt][r] = 0.f;

  s16x8 aQ0, aQ1;
  float lsum[4], inv[4];

  ASTAGE(0);

  // ---- PASS 1: per-head exp-sums ----
  for (int h = 0; h < 16; ++h) {
#pragma unroll
    for (int r = 0; r < 4; ++r) lsum[r] = 0.f;
#pragma unroll
    for (int ktp = 0; ktp < 8; ++ktp) {
      const int s = h * 8 + ktp;
      WAITL(); BAR();
      ASTAGE(s + 1);   // s+1 <= 128 always valid
      WAITV(2);
      __builtin_amdgcn_sched_barrier(0);
      if (ktp == 0) {
        aQ0 = *(const s16x8*)&Qs[(qh * 16 + fr) * 1032 + h * 64 + g * 8];
        aQ1 = *(const s16x8*)&Qs[(qh * 16 + fr) * 1032 + h * 64 + 32 + g * 8];
      }
      const unsigned short* Kbuf = Ks[s & 1];
      const int sw = (fr & 7) << 4;
#pragma unroll
      for (int ktsub = 0; ktsub < 2; ++ktsub) {
        const int row = kw * 32 + ktsub * 16 + fr;
        const s16x8 b0 = *(const s16x8*)&Kbuf[row * 64 + (((g * 16) ^ sw) >> 1)];
        const s16x8 b1 = *(const s16x8*)&Kbuf[row * 64 + (((64 + g * 16) ^ sw) >> 1)];
        f32x4 scv = (f32x4){0.f, 0.f, 0.f, 0.f};
        scv = MFMA16(aQ0, b0, scv);
        scv = MFMA16(aQ1, b1, scv);
#pragma unroll
        for (int r = 0; r < 4; ++r) lsum[r] += fast_exp2(scv[r]);
      }
    }
#pragma unroll
    for (int d = 1; d < 16; d <<= 1)
#pragma unroll
      for (int r = 0; r < 4; ++r) lsum[r] += __shfl_xor(lsum[r], d);
    if (fr == 0) {
#pragma unroll
      for (int r = 0; r < 4; ++r) sums[h][qh * 16 + g * 4 + r][kw] = lsum[r];
    }
  }

  // ---- PASS 2: normalize + head-average accumulate ----
  for (int h = 0; h < 16; ++h) {
#pragma unroll
    for (int ktp = 0; ktp < 8; ++ktp) {
      const int s = 128 + h * 8 + ktp;
      WAITL(); BAR();
      if (s < 255) { ASTAGE(s + 1); WAITV(2); } else { WAITV(0); }
      __builtin_amdgcn_sched_barrier(0);
      if (ktp == 0) {
        aQ0 = *(const s16x8*)&Qs[(qh * 16 + fr) * 1032 + h * 64 + g * 8];
        aQ1 = *(const s16x8*)&Qs[(qh * 16 + fr) * 1032 + h * 64 + 32 + g * 8];
#pragma unroll
        for (int r = 0; r < 4; ++r) {
          const f32x4 s0 = *(const f32x4*)&sums[h][qh * 16 + g * 4 + r][0];
          const f32x4 s1 = *(const f32x4*)&sums[h][qh * 16 + g * 4 + r][4];
          inv[r] = 1.0f / (16.0f * (((s0[0] + s0[1]) + (s0[2] + s0[3])) +
                                    ((s1[0] + s1[1]) + (s1[2] + s1[3]))));
        }
      }
      const unsigned short* Kbuf = Ks[s & 1];
      const int sw = (fr & 7) << 4;
#pragma unroll
      for (int ktsub = 0; ktsub < 2; ++ktsub) {
        const int row = kw * 32 + ktsub * 16 + fr;
        const s16x8 b0 = *(const s16x8*)&Kbuf[row * 64 + (((g * 16) ^ sw) >> 1)];
        const s16x8 b1 = *(const s16x8*)&Kbuf[row * 64 + (((64 + g * 16) ^ sw) >> 1)];
        f32x4 scv = (f32x4){0.f, 0.f, 0.f, 0.f};
        scv = MFMA16(aQ0, b0, scv);
        scv = MFMA16(aQ1, b1, scv);
#pragma unroll
        for (int r = 0; r < 4; ++r)
          avg[ktp * 2 + ktsub][r] += fast_exp2(scv[r]) * inv[r];
      }
    }
  }

  float* orow = avg_out + (size_t)(b * 2048 + q0 + qh * 16 + g * 4) * 2048 + kw * 256 + fr;
#pragma unroll
  for (int kt = 0; kt < 16; ++kt)
#pragma unroll
    for (int r = 0; r < 4; ++r)
      orow[(size_t)r * 2048 + kt * 16] = avg[kt][r];
#undef ASTAGE
}

// ---------------- Kernel 4: attn_out = avg_attn @ V  (bf16 out) -----------
__global__ __launch_bounds__(256, 2) void pv_out(
    const float* __restrict__ avg, const unsigned short* __restrict__ Vt,
    unsigned short* __restrict__ AOb) {
  const int t = threadIdx.x, lane = t & 63, w = t >> 6;
  const int fr = lane & 15, g = lane >> 4;
  const int bx = blockIdx.x;
  const int b = bx >> 5, q0 = (bx & 31) * 64;
  const float* ap = avg + (size_t)(b * 2048 + q0 + w * 16 + fr) * 2048 + g * 8;
  const unsigned short* vp = Vt + ((size_t)b * 64 + fr) * 2048 + g * 8;
  f32x4 acc[4];
#pragma unroll
  for (int i = 0; i < 4; ++i) acc[i] = (f32x4){0.f, 0.f, 0.f, 0.f};
  for (int kt = 0; kt < 64; ++kt) {
    const f32x4 alo = *(const f32x4*)(ap + kt * 32);
    const f32x4 ahi = *(const f32x4*)(ap + kt * 32 + 4);
    const s16x8 a = pack2(alo, ahi);
#pragma unroll
    for (int nt = 0; nt < 4; ++nt) {
      const s16x8 bfr = *(const s16x8*)(vp + (size_t)nt * 16 * 2048 + kt * 32);
      acc[nt] = MFMA16(a, bfr, acc[nt]);
    }
  }
#pragma unroll
  for (int nt = 0; nt < 4; ++nt) {
    const int d = nt * 16 + fr;
#pragma unroll
    for (int r = 0; r < 4; ++r)
      AOb[(size_t)(b * 2048 + q0 + w * 16 + g * 4 + r) * 64 + d] = f2bf(acc[nt][r]);
  }
}

// ---------------- Kernel 5: output = attn_out @ Wo^T + bo (f32 out) -------
__global__ __launch_bounds__(256, 2) void proj_o(
    const unsigned short* __restrict__ AOb, const float* __restrict__ Wo,
    const float* __restrict__ bo, float* __restrict__ out) {
  const int t = threadIdx.x, lane = t & 63, wid = t >> 6;
  const int wm = wid >> 1, wn = wid & 1;
  const int fr = lane & 15, g = lane >> 4;
  const int m0 = blockIdx.x * 128, n0 = blockIdx.y * 128;
  f32x4 acc[4][4];
#pragma unroll
  for (int i = 0; i < 4; ++i)
#pragma unroll
    for (int j = 0; j < 4; ++j) acc[i][j] = (f32x4){0.f, 0.f, 0.f, 0.f};
#pragma unroll
  for (int ks = 0; ks < 2; ++ks) {
    s16x8 af[4], bf[4];
#pragma unroll
    for (int mt = 0; mt < 4; ++mt)
      af[mt] = *(const s16x8*)(AOb + (size_t)(m0 + wm * 64 + mt * 16 + fr) * 64 + ks * 32 + g * 8);
#pragma unroll
    for (int nt = 0; nt < 4; ++nt) {
      const float* wp = Wo + (size_t)(n0 + wn * 64 + nt * 16 + fr) * 64 + ks * 32 + g * 8;
      bf[nt] = pack2(*(const f32x4*)wp, *(const f32x4*)(wp + 4));
    }
#pragma unroll
    for (int mt = 0; mt < 4; ++mt)
#pragma unroll
      for (int nt = 0; nt < 4; ++nt)
        acc[mt][nt] = MFMA16(af[mt], bf[nt], acc[mt][nt]);
  }
#pragma unroll
  for (int nt = 0; nt < 4; ++nt) {
    const int col = n0 + wn * 64 + nt * 16 + fr;
    const float bb = bo[col];
#pragma unroll
    for (int mt = 0; mt < 4; ++mt) {
      const int row = m0 + wm * 64 + mt * 16 + g * 4;
#pragma unroll
      for (int r = 0; r < 4; ++r)
        out[(size_t)(row + r) * 1024 + col] = acc[mt][nt][r] + bb;
    }
  }
}

extern "C" void kernel_launch(void* const* d_in, const int* in_sizes, int n_in,
                              void* d_out, int out_size, void* d_ws, size_t ws_size,
                              hipStream_t stream) {
  const float* query = (const float*)d_in[0];
  const float* key_in = (const float*)d_in[1];
  const float* value = (const float*)d_in[2];
  const float* Wq = (const float*)d_in[3];
  const float* bq = (const float*)d_in[4];
  const float* Wk = (const float*)d_in[5];
  const float* bk = (const float*)d_in[6];
  const float* Wv = (const float*)d_in[7];
  const float* bv = (const float*)d_in[8];
  const float* Wo = (const float*)d_in[9];
  const float* bo = (const float*)d_in[10];

  unsigned short* Qb = (unsigned short*)d_ws;
  unsigned short* Kb = Qb + 8388608;
  unsigned short* Vt = Kb + 8388608;
  unsigned short* AOb = Vt + 524288;

  float* out = (float*)d_out;
  float* avg_out = out + 8388608;

  // cast scratch parked in the avg region (consumed before attn_avg writes it)
  unsigned short* qbf = (unsigned short*)avg_out;
  unsigned short* kbf = qbf + 8388608;
  unsigned short* wqb = kbf + 8388608;
  unsigned short* wkb = wqb + 1048576;

  hipLaunchKernelGGL(cast_bf16, dim3(2304), dim3(256), 0, stream,
                     query, key_in, Wq, Wk, qbf, kbf, wqb, wkb);
  hipLaunchKernelGGL(proj_qk, dim3(64, 8, 2), dim3(256), 0, stream,
                     qbf, kbf, wqb, wkb, bq, bk, Qb, Kb);
  hipLaunchKernelGGL(proj_v, dim3(128), dim3(256), 0, stream, value, Wv, bv, Vt);
  hipLaunchKernelGGL(attn_avg, dim3(256), dim3(1024), 0, stream, Qb, Kb, avg_out);
  hipLaunchKernelGGL(pv_out, dim3(128), dim3(256), 0, stream, avg_out, Vt, AOb);
  hipLaunchKernelGGL(proj_o, dim3(64, 8), dim3(256), 0, stream, AOb, Wo, bo, out);
}